// Round 1
// baseline (684.162 us; speedup 1.0000x reference)
//
#include <hip/hip_runtime.h>
#include <math.h>

#define HW 128
#define NPIX (HW * HW)
#define CIN 64
#define COUT 64
#define NB 8

// pixel tile: 4 rows x 64 cols per block (256 threads, 1 thread = 1 pixel)
#define TR 4
#define TC 64
// halo tile per channel: 6 x 66, col padded to 68
#define HR (TR + 2)
#define HC (TC + 2)
#define HCP 68

// ------------------------------------------------------------------
// global average pool: one block per (b, n)
__global__ __launch_bounds__(256) void k_gpool(const float* __restrict__ x,
                                               float* __restrict__ g) {
  int bn = blockIdx.x;  // 0..511
  const float* p = x + (size_t)bn * NPIX;
  float s = 0.f;
  #pragma unroll 4
  for (int i = threadIdx.x; i < NPIX; i += 256) s += p[i];
  #pragma unroll
  for (int o = 32; o > 0; o >>= 1) s += __shfl_down(s, o, 64);
  __shared__ float red[4];
  int lane = threadIdx.x & 63, wid = threadIdx.x >> 6;
  if (lane == 0) red[wid] = s;
  __syncthreads();
  if (threadIdx.x == 0)
    g[bn] = (red[0] + red[1] + red[2] + red[3]) * (1.0f / NPIX);
}

// ------------------------------------------------------------------
// dynamic bias: one block (64 threads) per batch
__global__ __launch_bounds__(64) void k_bias(const float* __restrict__ g,
                                             const float* __restrict__ a3w1,
                                             const float* __restrict__ a3b1,
                                             const float* __restrict__ a3w2,
                                             const float* __restrict__ a3b2,
                                             float* __restrict__ bias) {
  int b = blockIdx.x;
  int t = threadIdx.x;
  __shared__ float h[64];
  float s = a3b1[t];
  #pragma unroll
  for (int n = 0; n < 64; n++) s += a3w1[t * 64 + n] * g[b * 64 + n];
  h[t] = fmaxf(s, 0.f);
  __syncthreads();
  float s2 = a3b2[t];
  #pragma unroll
  for (int c = 0; c < 64; c++) s2 += a3w2[t * 64 + c] * h[c];
  bias[b * 64 + t] = s2;
}

// ------------------------------------------------------------------
// attention weights: atw[b][9][H][W] = sigmoid(1x1(relu(1x1(relu(conv3x3(x))))))
__global__ __launch_bounds__(256) void k_attn(const float* __restrict__ x,
                                              const float* __restrict__ w1,
                                              const float* __restrict__ b1,
                                              const float* __restrict__ w2,
                                              const float* __restrict__ b2,
                                              const float* __restrict__ w3,
                                              const float* __restrict__ b3,
                                              float* __restrict__ atw) {
  int b = blockIdx.y;
  int ty = blockIdx.x >> 1;   // 0..31
  int tx = blockIdx.x & 1;    // 0..1
  int ti = threadIdx.x >> 6;  // 0..3 (one wave per row)
  int tj = threadIdx.x & 63;  // 0..63
  int i = ty * TR + ti, j = tx * TC + tj;

  __shared__ float xt[8][HR][HCP];
  float s[9];
  #pragma unroll
  for (int q = 0; q < 9; q++) s[q] = 0.f;

  #pragma unroll 1
  for (int nc = 0; nc < 8; nc++) {
    __syncthreads();
    for (int idx = threadIdx.x; idx < 8 * HR * HC; idx += 256) {
      int c = idx / (HR * HC);
      int rem = idx - c * (HR * HC);
      int r = rem / HC;
      int col = rem - r * HC;
      int gi = ty * TR + r - 1, gj = tx * TC + col - 1;
      float v = 0.f;
      if (gi >= 0 && gi < HW && gj >= 0 && gj < HW)
        v = x[(((size_t)b * CIN + nc * 8 + c) * HW + gi) * HW + gj];
      xt[c][r][col] = v;
    }
    __syncthreads();
    #pragma unroll 1
    for (int c = 0; c < 8; c++) {
      int n = nc * 8 + c;
      float xv[9];
      #pragma unroll
      for (int di = 0; di < 3; di++)
        #pragma unroll
        for (int dj = 0; dj < 3; dj++)
          xv[di * 3 + dj] = xt[c][ti + di][tj + dj];
      #pragma unroll
      for (int q = 0; q < 9; q++) {
        #pragma unroll
        for (int t = 0; t < 9; t++)
          s[q] += w1[(q * 64 + n) * 9 + t] * xv[t];  // uniform addr -> s_load
      }
    }
  }

  float t1[9], t2[9];
  #pragma unroll
  for (int q = 0; q < 9; q++) t1[q] = fmaxf(s[q] + b1[q], 0.f);
  #pragma unroll
  for (int r = 0; r < 9; r++) {
    float a = b2[r];
    #pragma unroll
    for (int q = 0; q < 9; q++) a += w2[r * 9 + q] * t1[q];
    t2[r] = fmaxf(a, 0.f);
  }
  #pragma unroll
  for (int r = 0; r < 9; r++) {
    float a = b3[r];
    #pragma unroll
    for (int q = 0; q < 9; q++) a += w3[r * 9 + q] * t2[q];
    atw[((size_t)(b * 9 + r) * HW + i) * HW + j] = 1.f / (1.f + expf(-a));
  }
}

// ------------------------------------------------------------------
// main conv: y[b,m,i,j] = sum_n sum_p weight[m,n,p] * x[b,n,i+di-1,j+dj-1] * atw[b,p,i,j] + bias[b,m]
// one thread = one pixel, all 64 output channels in registers
__global__ __launch_bounds__(256) void k_main(const float* __restrict__ x,
                                              const float* __restrict__ wgt,
                                              const float* __restrict__ atw,
                                              const float* __restrict__ bias,
                                              float* __restrict__ out) {
  int b = blockIdx.y;
  int ty = blockIdx.x >> 1;
  int tx = blockIdx.x & 1;
  int ti = threadIdx.x >> 6;
  int tj = threadIdx.x & 63;
  int i = ty * TR + ti, j = tx * TC + tj;

  float aw[9];
  #pragma unroll
  for (int p = 0; p < 9; p++)
    aw[p] = atw[((size_t)(b * 9 + p) * HW + i) * HW + j];

  float acc[64];
  #pragma unroll
  for (int m = 0; m < 64; m++) acc[m] = 0.f;

  __shared__ float xt[8][HR][HCP];

  #pragma unroll 1
  for (int nc = 0; nc < 8; nc++) {
    __syncthreads();
    for (int idx = threadIdx.x; idx < 8 * HR * HC; idx += 256) {
      int c = idx / (HR * HC);
      int rem = idx - c * (HR * HC);
      int r = rem / HC;
      int col = rem - r * HC;
      int gi = ty * TR + r - 1, gj = tx * TC + col - 1;
      float v = 0.f;
      if (gi >= 0 && gi < HW && gj >= 0 && gj < HW)
        v = x[(((size_t)b * CIN + nc * 8 + c) * HW + gi) * HW + gj];
      xt[c][r][col] = v;
    }
    __syncthreads();
    #pragma unroll 1
    for (int c = 0; c < 8; c++) {
      int n = nc * 8 + c;
      float xp[9];
      #pragma unroll
      for (int di = 0; di < 3; di++)
        #pragma unroll
        for (int dj = 0; dj < 3; dj++)
          xp[di * 3 + dj] = xt[c][ti + di][tj + dj] * aw[di * 3 + dj];
      const float* wn = wgt + n * 9;
      #pragma unroll
      for (int m = 0; m < 64; m++) {
        #pragma unroll
        for (int p = 0; p < 9; p++)
          acc[m] += wn[m * 576 + p] * xp[p];  // uniform addr -> s_load
      }
    }
  }

  #pragma unroll
  for (int m = 0; m < 64; m++) {
    out[(((size_t)b * COUT + m) * HW + i) * HW + j] = acc[m] + bias[b * 64 + m];
  }
}

// ------------------------------------------------------------------
extern "C" void kernel_launch(void* const* d_in, const int* in_sizes, int n_in,
                              void* d_out, int out_size, void* d_ws, size_t ws_size,
                              hipStream_t stream) {
  const float* x    = (const float*)d_in[0];
  const float* a1w1 = (const float*)d_in[1];
  const float* a1b1 = (const float*)d_in[2];
  const float* a1w2 = (const float*)d_in[3];
  const float* a1b2 = (const float*)d_in[4];
  const float* a1w3 = (const float*)d_in[5];
  const float* a1b3 = (const float*)d_in[6];
  const float* a3w1 = (const float*)d_in[7];
  const float* a3b1 = (const float*)d_in[8];
  const float* a3w2 = (const float*)d_in[9];
  const float* a3b2 = (const float*)d_in[10];
  const float* wgt  = (const float*)d_in[11];
  float* out = (float*)d_out;

  float* ws = (float*)d_ws;
  float* atw  = ws;                          // NB*9*NPIX = 1179648 floats
  float* g    = ws + (size_t)NB * 9 * NPIX;  // 512 floats
  float* bias = g + NB * CIN;                // 512 floats

  k_gpool<<<dim3(NB * CIN), dim3(256), 0, stream>>>(x, g);
  k_bias<<<dim3(NB), dim3(64), 0, stream>>>(g, a3w1, a3b1, a3w2, a3b2, bias);
  dim3 grid(64, NB);
  k_attn<<<grid, dim3(256), 0, stream>>>(x, a1w1, a1b1, a1w2, a1b2, a1w3, a1b3, atw);
  k_main<<<grid, dim3(256), 0, stream>>>(x, wgt, atw, bias, out);
}

// Round 2
// 171.919 us; speedup vs baseline: 3.9795x; 3.9795x over previous
//
#include <hip/hip_runtime.h>
#include <hip/hip_bf16.h>
#include <math.h>

#define HW 128
#define NPIX (HW * HW)
#define CIN 64
#define COUT 64
#define NB 8

typedef __attribute__((ext_vector_type(8))) short bf16x8;
typedef __attribute__((ext_vector_type(4))) float f32x4;

// f32 -> bf16 bits, RNE
static __device__ __forceinline__ short f2bf(float v) {
  union { float f; unsigned u; } a; a.f = v;
  unsigned r = a.u + 0x7fffu + ((a.u >> 16) & 1u);
  return (short)(r >> 16);
}

// ------------------------------------------------------------------
// weight prepack: wgt[m][n][p] f32 -> Apack[p][m][n] bf16
__global__ __launch_bounds__(256) void k_pack(const float* __restrict__ wgt,
                                              short* __restrict__ Apack) {
  int idx = blockIdx.x * 256 + threadIdx.x;
  if (idx >= 9 * 64 * 64) return;
  int p = idx >> 12;
  int m = (idx >> 6) & 63;
  int n = idx & 63;
  Apack[idx] = f2bf(wgt[(m * 64 + n) * 9 + p]);
}

// ------------------------------------------------------------------
// global average pool: one block per (b, n)
__global__ __launch_bounds__(256) void k_gpool(const float* __restrict__ x,
                                               float* __restrict__ g) {
  int bn = blockIdx.x;
  const float* p = x + (size_t)bn * NPIX;
  float s = 0.f;
  #pragma unroll 4
  for (int i = threadIdx.x; i < NPIX; i += 256) s += p[i];
  #pragma unroll
  for (int o = 32; o > 0; o >>= 1) s += __shfl_down(s, o, 64);
  __shared__ float red[4];
  int lane = threadIdx.x & 63, wid = threadIdx.x >> 6;
  if (lane == 0) red[wid] = s;
  __syncthreads();
  if (threadIdx.x == 0)
    g[bn] = (red[0] + red[1] + red[2] + red[3]) * (1.0f / NPIX);
}

// ------------------------------------------------------------------
// dynamic bias: one block (64 threads) per batch
__global__ __launch_bounds__(64) void k_bias(const float* __restrict__ g,
                                             const float* __restrict__ a3w1,
                                             const float* __restrict__ a3b1,
                                             const float* __restrict__ a3w2,
                                             const float* __restrict__ a3b2,
                                             float* __restrict__ bias) {
  int b = blockIdx.x;
  int t = threadIdx.x;
  __shared__ float h[64];
  float s = a3b1[t];
  #pragma unroll
  for (int n = 0; n < 64; n++) s += a3w1[t * 64 + n] * g[b * 64 + n];
  h[t] = fmaxf(s, 0.f);
  __syncthreads();
  float s2 = a3b2[t];
  #pragma unroll
  for (int c = 0; c < 64; c++) s2 += a3w2[t * 64 + c] * h[c];
  bias[b * 64 + t] = s2;
}

// ------------------------------------------------------------------
// attention weights (unchanged round-1 version; next round's target)
#define TR 4
#define TC 64
#define HR (TR + 2)
#define HC (TC + 2)
#define HCP 68
__global__ __launch_bounds__(256) void k_attn(const float* __restrict__ x,
                                              const float* __restrict__ w1,
                                              const float* __restrict__ b1,
                                              const float* __restrict__ w2,
                                              const float* __restrict__ b2,
                                              const float* __restrict__ w3,
                                              const float* __restrict__ b3,
                                              float* __restrict__ atw) {
  int b = blockIdx.y;
  int ty = blockIdx.x >> 1;
  int tx = blockIdx.x & 1;
  int ti = threadIdx.x >> 6;
  int tj = threadIdx.x & 63;
  int i = ty * TR + ti, j = tx * TC + tj;

  __shared__ float xt[8][HR][HCP];
  float s[9];
  #pragma unroll
  for (int q = 0; q < 9; q++) s[q] = 0.f;

  #pragma unroll 1
  for (int nc = 0; nc < 8; nc++) {
    __syncthreads();
    for (int idx = threadIdx.x; idx < 8 * HR * HC; idx += 256) {
      int c = idx / (HR * HC);
      int rem = idx - c * (HR * HC);
      int r = rem / HC;
      int col = rem - r * HC;
      int gi = ty * TR + r - 1, gj = tx * TC + col - 1;
      float v = 0.f;
      if (gi >= 0 && gi < HW && gj >= 0 && gj < HW)
        v = x[(((size_t)b * CIN + nc * 8 + c) * HW + gi) * HW + gj];
      xt[c][r][col] = v;
    }
    __syncthreads();
    #pragma unroll 1
    for (int c = 0; c < 8; c++) {
      int n = nc * 8 + c;
      float xv[9];
      #pragma unroll
      for (int di = 0; di < 3; di++)
        #pragma unroll
        for (int dj = 0; dj < 3; dj++)
          xv[di * 3 + dj] = xt[c][ti + di][tj + dj];
      #pragma unroll
      for (int q = 0; q < 9; q++) {
        #pragma unroll
        for (int t = 0; t < 9; t++)
          s[q] += w1[(q * 64 + n) * 9 + t] * xv[t];
      }
    }
  }

  float t1[9], t2[9];
  #pragma unroll
  for (int q = 0; q < 9; q++) t1[q] = fmaxf(s[q] + b1[q], 0.f);
  #pragma unroll
  for (int r = 0; r < 9; r++) {
    float a = b2[r];
    #pragma unroll
    for (int q = 0; q < 9; q++) a += w2[r * 9 + q] * t1[q];
    t2[r] = fmaxf(a, 0.f);
  }
  #pragma unroll
  for (int r = 0; r < 9; r++) {
    float a = b3[r];
    #pragma unroll
    for (int q = 0; q < 9; q++) a += w3[r * 9 + q] * t2[q];
    atw[((size_t)(b * 9 + r) * HW + i) * HW + j] = 1.f / (1.f + expf(-a));
  }
}

// ------------------------------------------------------------------
// main conv via MFMA: 9 partial GEMMs (one per tap p)
//   Y[m, pix] += A[p][m][n] * (x[n, pix shifted by p] * aw_eff[p, pix])
// wave = 1 pixel row x 32 cols (2 groups of 16); block = 4 waves = 4 rows.
__global__ __launch_bounds__(256) void k_main_mfma(
    const float* __restrict__ x, const short* __restrict__ Apack,
    const float* __restrict__ atw, const float* __restrict__ bias,
    float* __restrict__ out) {
  int b = blockIdx.y;
  int ty = blockIdx.x >> 2;   // row tile 0..31
  int tx = blockIdx.x & 3;    // col strip 0..3
  int wid = threadIdx.x >> 6;
  int lane = threadIdx.x & 63;
  int i = ty * 4 + wid;       // pixel row (uniform per wave)
  int lp = lane & 15;         // pixel within 16-group
  int kq = lane >> 4;         // k-quad 0..3
  int colbase = tx * 32;

  f32x4 acc[2][4];
  #pragma unroll
  for (int g = 0; g < 2; g++)
    #pragma unroll
    for (int mt = 0; mt < 4; mt++) acc[g][mt] = (f32x4){0.f, 0.f, 0.f, 0.f};

  const float* xb = x + (size_t)b * CIN * NPIX;

  #pragma unroll
  for (int p = 0; p < 9; p++) {
    const int di = p / 3, dj = p % 3;
    // A fragments for this tap: lane holds A[p][mt*16+lp][ck*32+kq*8 .. +7]
    bf16x8 af[2][4];
    #pragma unroll
    for (int ck = 0; ck < 2; ck++)
      #pragma unroll
      for (int mt = 0; mt < 4; mt++)
        af[ck][mt] = *(const bf16x8*)(Apack +
            ((p * 64 + mt * 16 + lp) * 64 + ck * 32 + kq * 8));

    int ri = i + di - 1;
    int ric = min(max(ri, 0), HW - 1);
    bool row_ok = (ri >= 0) && (ri < HW);

    #pragma unroll
    for (int g = 0; g < 2; g++) {
      int j = colbase + g * 16 + lp;   // this lane's pixel col
      int cj = j + dj - 1;
      int cjc = min(max(cj, 0), HW - 1);
      bool ok = row_ok && (cj >= 0) && (cj < HW);
      float awv = ok ? atw[((size_t)(b * 9 + p) * HW + i) * HW + j] : 0.f;

      const float* xpix = xb + (size_t)(kq * 8) * NPIX + ric * HW + cjc;
      #pragma unroll
      for (int ck = 0; ck < 2; ck++) {
        const float* xp2 = xpix + (size_t)(ck * 32) * NPIX;
        bf16x8 bf;
        #pragma unroll
        for (int jj = 0; jj < 8; jj++)
          bf[jj] = f2bf(xp2[(size_t)jj * NPIX] * awv);
        #pragma unroll
        for (int mt = 0; mt < 4; mt++)
          acc[g][mt] = __builtin_amdgcn_mfma_f32_16x16x32_bf16(
              af[ck][mt], bf, acc[g][mt], 0, 0, 0);
      }
    }
  }

  // bias values for this lane's 16 output channels
  float bval[4][4];
  #pragma unroll
  for (int mt = 0; mt < 4; mt++)
    #pragma unroll
    for (int r = 0; r < 4; r++)
      bval[mt][r] = bias[b * 64 + mt * 16 + kq * 4 + r];

  // C layout: col(pixel) = lane&15, row(m) = (lane>>4)*4 + reg
  #pragma unroll
  for (int g = 0; g < 2; g++) {
    int j = colbase + g * 16 + lp;
    #pragma unroll
    for (int mt = 0; mt < 4; mt++)
      #pragma unroll
      for (int r = 0; r < 4; r++) {
        int m = mt * 16 + kq * 4 + r;
        out[(((size_t)b * COUT + m) * HW + i) * HW + j] =
            acc[g][mt][r] + bval[mt][r];
      }
  }
}

// ------------------------------------------------------------------
extern "C" void kernel_launch(void* const* d_in, const int* in_sizes, int n_in,
                              void* d_out, int out_size, void* d_ws, size_t ws_size,
                              hipStream_t stream) {
  const float* x    = (const float*)d_in[0];
  const float* a1w1 = (const float*)d_in[1];
  const float* a1b1 = (const float*)d_in[2];
  const float* a1w2 = (const float*)d_in[3];
  const float* a1b2 = (const float*)d_in[4];
  const float* a1w3 = (const float*)d_in[5];
  const float* a1b3 = (const float*)d_in[6];
  const float* a3w1 = (const float*)d_in[7];
  const float* a3b1 = (const float*)d_in[8];
  const float* a3w2 = (const float*)d_in[9];
  const float* a3b2 = (const float*)d_in[10];
  const float* wgt  = (const float*)d_in[11];
  float* out = (float*)d_out;

  float* ws = (float*)d_ws;
  float* atw   = ws;                           // 8*9*16384 floats
  float* g     = ws + (size_t)NB * 9 * NPIX;   // 512
  float* bias  = g + NB * CIN;                 // 512
  short* Apack = (short*)(bias + NB * COUT);   // 9*64*64 bf16

  k_pack<<<dim3(144), dim3(256), 0, stream>>>(wgt, Apack);
  k_gpool<<<dim3(NB * CIN), dim3(256), 0, stream>>>(x, g);
  k_bias<<<dim3(NB), dim3(64), 0, stream>>>(g, a3w1, a3b1, a3w2, a3b2, bias);
  dim3 agrid(64, NB);
  k_attn<<<agrid, dim3(256), 0, stream>>>(x, a1w1, a1b1, a1w2, a1b2, a1w3, a1b3, atw);
  dim3 mgrid(128, NB);
  k_main_mfma<<<mgrid, dim3(256), 0, stream>>>(x, Apack, atw, bias, out);
}

// Round 3
// 84.251 us; speedup vs baseline: 8.1206x; 2.0406x over previous
//
#include <hip/hip_runtime.h>
#include <hip/hip_bf16.h>
#include <math.h>

#define HW 128
#define NPIX (HW * HW)
#define NB 8

#define TROWS 8
#define TCOLS 32
#define HR2 10
#define HC2 34
#define NPXT (HR2 * HC2)  // 340

typedef __attribute__((ext_vector_type(8))) short bf16x8;
typedef __attribute__((ext_vector_type(4))) float f32x4;

// f32 -> bf16 bits, RNE
static __device__ __forceinline__ short f2bf(float v) {
  union { float f; unsigned u; } a; a.f = v;
  unsigned r = a.u + 0x7fffu + ((a.u >> 16) & 1u);
  return (short)(r >> 16);
}
static __device__ __forceinline__ float bfbits2f(unsigned u) {
  union { unsigned u; float f; } a; a.u = u; return a.f;
}

// ------------------------------------------------------------------
// prepack: Apack[p][64 m][64 n], A1pack[p][16 q][64 n] (q>=9 rows zero)
__global__ __launch_bounds__(256) void k_pack(const float* __restrict__ wgt,
                                              const float* __restrict__ a1w1,
                                              short* __restrict__ Apack,
                                              short* __restrict__ A1pack) {
  int idx = blockIdx.x * 256 + threadIdx.x;
  if (idx < 9 * 64 * 64) {
    int p = idx >> 12, m = (idx >> 6) & 63, n = idx & 63;
    Apack[idx] = f2bf(wgt[(m * 64 + n) * 9 + p]);
  }
  if (idx < 9 * 16 * 64) {
    int p = idx >> 10, q = (idx >> 6) & 15, n = idx & 63;
    A1pack[idx] = (q < 9) ? f2bf(a1w1[(q * 64 + n) * 9 + p]) : (short)0;
  }
}

// ------------------------------------------------------------------
// global average pool: one block per (b, n), float4 loads
__global__ __launch_bounds__(256) void k_gpool(const float* __restrict__ x,
                                               float* __restrict__ g) {
  int bn = blockIdx.x;
  const float4* p = (const float4*)(x + (size_t)bn * NPIX);
  float s = 0.f;
  #pragma unroll 4
  for (int i = threadIdx.x; i < NPIX / 4; i += 256) {
    float4 v = p[i];
    s += v.x + v.y + v.z + v.w;
  }
  #pragma unroll
  for (int o = 32; o > 0; o >>= 1) s += __shfl_down(s, o, 64);
  __shared__ float red[4];
  int lane = threadIdx.x & 63, wid = threadIdx.x >> 6;
  if (lane == 0) red[wid] = s;
  __syncthreads();
  if (threadIdx.x == 0)
    g[bn] = (red[0] + red[1] + red[2] + red[3]) * (1.0f / NPIX);
}

// ------------------------------------------------------------------
// dynamic bias: one block (64 threads) per batch
__global__ __launch_bounds__(64) void k_bias(const float* __restrict__ g,
                                             const float* __restrict__ a3w1,
                                             const float* __restrict__ a3b1,
                                             const float* __restrict__ a3w2,
                                             const float* __restrict__ a3b2,
                                             float* __restrict__ bias) {
  int b = blockIdx.x;
  int t = threadIdx.x;
  __shared__ float h[64];
  float s = a3b1[t];
  #pragma unroll
  for (int n = 0; n < 64; n++) s += a3w1[t * 64 + n] * g[b * 64 + n];
  h[t] = fmaxf(s, 0.f);
  __syncthreads();
  float s2 = a3b2[t];
  #pragma unroll
  for (int c = 0; c < 64; c++) s2 += a3w2[t * 64 + c] * h[c];
  bias[b * 64 + t] = s2;
}

// ------------------------------------------------------------------
// fused: stage x tile -> conv1 MFMA -> per-pixel MLP (atw) -> main MFMA
// block: 512 thr = 8 waves; tile 8 rows x 32 cols; wave = 1 row x 32 cols
__global__ __launch_bounds__(512, 4) void k_fused(
    const float* __restrict__ x, const short* __restrict__ Apack,
    const short* __restrict__ A1pack,
    const float* __restrict__ b1p, const float* __restrict__ w2p,
    const float* __restrict__ b2p, const float* __restrict__ w3p,
    const float* __restrict__ b3p,
    const float* __restrict__ bias, float* __restrict__ out) {
  __shared__ short xt[NPXT * 64];      // [pix][64 ch] bf16, byte^((pix&7)<<4)
  __shared__ float ab[TROWS][32][17];  // a-values then atw, per wave

  int b = blockIdx.y;
  int ty = blockIdx.x >> 2, tx = blockIdx.x & 3;
  int tid = threadIdx.x;
  int wid = tid >> 6, lane = tid & 63;
  int lp = lane & 15, kq = lane >> 4;
  int row0 = ty * TROWS, col0 = tx * TCOLS;
  const float* xb = x + (size_t)b * 64 * NPIX;

  // ---- stage halo tile (zero-padded) as bf16, ch-contiguous, swizzled
  for (int it = tid; it < NPXT * 64; it += 512) {
    int ch = it / NPXT;
    int pix = it - ch * NPXT;
    int r = pix / HC2;
    int c = pix - r * HC2;
    int gi = row0 - 1 + r, gj = col0 - 1 + c;
    float v = 0.f;
    if (gi >= 0 && gi < HW && gj >= 0 && gj < HW)
      v = xb[(size_t)ch * NPIX + gi * HW + gj];
    int byteoff = (pix * 128 + ch * 2) ^ ((pix & 7) << 4);
    *(short*)((char*)xt + byteoff) = f2bf(v);
  }
  __syncthreads();

  // ---- phase 1: conv1 via MFMA (M=16 padded, K=576 over 9 taps x 64 ch)
  f32x4 acc1[2];
  #pragma unroll
  for (int g = 0; g < 2; g++) acc1[g] = (f32x4){0.f, 0.f, 0.f, 0.f};

  #pragma unroll
  for (int p = 0; p < 9; p++) {
    const int di = p / 3, dj = p % 3;
    int rt = wid + di;
    #pragma unroll
    for (int ck = 0; ck < 2; ck++) {
      bf16x8 af1 = *(const bf16x8*)(A1pack + (p * 16 + lp) * 64 + ck * 32 + kq * 8);
      #pragma unroll
      for (int g = 0; g < 2; g++) {
        int pix = rt * HC2 + g * 16 + lp + dj;
        int byteoff = (pix * 128 + ck * 64 + kq * 16) ^ ((pix & 7) << 4);
        bf16x8 bf = *(const bf16x8*)((const char*)xt + byteoff);
        acc1[g] = __builtin_amdgcn_mfma_f32_16x16x32_bf16(af1, bf, acc1[g], 0, 0, 0);
      }
    }
  }
  // scatter a (pre-activation) to ab[wave][pixel][q]
  #pragma unroll
  for (int g = 0; g < 2; g++)
    #pragma unroll
    for (int r = 0; r < 4; r++)
      ab[wid][g * 16 + lp][kq * 4 + r] = acc1[g][r];
  __syncthreads();

  // ---- phase 2: per-pixel MLP -> atw (in place in ab)
  if (lane < 32) {
    float a[9], t1[9], t2[9];
    #pragma unroll
    for (int q = 0; q < 9; q++) a[q] = ab[wid][lane][q];
    #pragma unroll
    for (int q = 0; q < 9; q++) t1[q] = fmaxf(a[q] + b1p[q], 0.f);
    #pragma unroll
    for (int r = 0; r < 9; r++) {
      float s = b2p[r];
      #pragma unroll
      for (int q = 0; q < 9; q++) s += w2p[r * 9 + q] * t1[q];
      t2[r] = fmaxf(s, 0.f);
    }
    #pragma unroll
    for (int r = 0; r < 9; r++) {
      float s = b3p[r];
      #pragma unroll
      for (int q = 0; q < 9; q++) s += w3p[r * 9 + q] * t2[q];
      ab[wid][lane][r] = 1.f / (1.f + __expf(-s));
    }
  }
  __syncthreads();

  // ---- phase 3: main conv via MFMA with atw-scaled fragments
  f32x4 acc[2][4];
  #pragma unroll
  for (int g = 0; g < 2; g++)
    #pragma unroll
    for (int mt = 0; mt < 4; mt++) acc[g][mt] = (f32x4){0.f, 0.f, 0.f, 0.f};

  #pragma unroll
  for (int p = 0; p < 9; p++) {
    const int di = p / 3, dj = p % 3;
    int rt = wid + di;
    bf16x8 frag[2][2];
    #pragma unroll
    for (int g = 0; g < 2; g++) {
      float awv = ab[wid][g * 16 + lp][p];
      int pix = rt * HC2 + g * 16 + lp + dj;
      #pragma unroll
      for (int ck = 0; ck < 2; ck++) {
        int byteoff = (pix * 128 + ck * 64 + kq * 16) ^ ((pix & 7) << 4);
        union { bf16x8 v; unsigned u[4]; } in, op;
        in.v = *(const bf16x8*)((const char*)xt + byteoff);
        #pragma unroll
        for (int d = 0; d < 4; d++) {
          float lo = bfbits2f(in.u[d] << 16) * awv;
          float hi = bfbits2f(in.u[d] & 0xffff0000u) * awv;
          __hip_bfloat162 pk = __float22bfloat162_rn(make_float2(lo, hi));
          union { __hip_bfloat162 h; unsigned u; } cv; cv.h = pk;
          op.u[d] = cv.u;
        }
        frag[g][ck] = op.v;
      }
    }
    #pragma unroll
    for (int mt = 0; mt < 4; mt++) {
      #pragma unroll
      for (int ck = 0; ck < 2; ck++) {
        bf16x8 af = *(const bf16x8*)(Apack + ((p * 64 + mt * 16 + lp) * 64 + ck * 32 + kq * 8));
        #pragma unroll
        for (int g = 0; g < 2; g++)
          acc[g][mt] = __builtin_amdgcn_mfma_f32_16x16x32_bf16(af, frag[g][ck], acc[g][mt], 0, 0, 0);
      }
    }
  }

  // ---- epilogue: bias + store
  int i = row0 + wid;
  #pragma unroll
  for (int mt = 0; mt < 4; mt++) {
    #pragma unroll
    for (int r = 0; r < 4; r++) {
      int m = mt * 16 + kq * 4 + r;
      float bv = bias[b * 64 + m];
      #pragma unroll
      for (int g = 0; g < 2; g++) {
        int j = col0 + g * 16 + lp;
        out[(((size_t)b * 64 + m) * HW + i) * HW + j] = acc[g][mt][r] + bv;
      }
    }
  }
}

// ------------------------------------------------------------------
extern "C" void kernel_launch(void* const* d_in, const int* in_sizes, int n_in,
                              void* d_out, int out_size, void* d_ws, size_t ws_size,
                              hipStream_t stream) {
  const float* x    = (const float*)d_in[0];
  const float* a1w1 = (const float*)d_in[1];
  const float* a1b1 = (const float*)d_in[2];
  const float* a1w2 = (const float*)d_in[3];
  const float* a1b2 = (const float*)d_in[4];
  const float* a1w3 = (const float*)d_in[5];
  const float* a1b3 = (const float*)d_in[6];
  const float* a3w1 = (const float*)d_in[7];
  const float* a3b1 = (const float*)d_in[8];
  const float* a3w2 = (const float*)d_in[9];
  const float* a3b2 = (const float*)d_in[10];
  const float* wgt  = (const float*)d_in[11];
  float* out = (float*)d_out;

  float* ws = (float*)d_ws;
  float* g     = ws;                          // 512
  float* bias  = g + NB * 64;                 // 512
  short* Apack = (short*)(bias + NB * 64);    // 9*64*64
  short* A1pack = Apack + 9 * 64 * 64;        // 9*16*64

  k_pack<<<dim3(144), dim3(256), 0, stream>>>(wgt, a1w1, Apack, A1pack);
  k_gpool<<<dim3(NB * 64), dim3(256), 0, stream>>>(x, g);
  k_bias<<<dim3(NB), dim3(64), 0, stream>>>(g, a3w1, a3b1, a3w2, a3b2, bias);
  dim3 fgrid(64, NB);  // 16 row-tiles x 4 col-strips, per batch
  k_fused<<<fgrid, dim3(512), 0, stream>>>(x, Apack, A1pack,
                                           a1b1, a1w2, a1b2, a1w3, a1b3,
                                           bias, out);
}